// Round 1
// baseline (284.308 us; speedup 1.0000x reference)
//
#include <hip/hip_runtime.h>
#include <math.h>

#define G_MAX 512  // LDS capacity for GT boxes; setup uses G=300

__device__ __forceinline__ float waveSum(float v) {
#pragma unroll
  for (int o = 32; o > 0; o >>= 1) v += __shfl_down(v, o, 64);
  return v;
}

// smooth-L1 with sigma=3 (s2=9)
__device__ __forceinline__ float huber9(float x) {
  float ax = fabsf(x);
  return (ax < (1.0f / 9.0f)) ? 4.5f * x * x : ax - (0.5f / 9.0f);
}

__global__ __launch_bounds__(256) void retina_main(
    const float* __restrict__ pred_cls,   // (n, A, 2)
    const float* __restrict__ rpn_num,    // (n, A, 2)
    const float* __restrict__ pred_reg,   // (n, A, 8)
    const float* __restrict__ anchors,    // (A, 4)
    const float* __restrict__ rpn_iou,    // (n, A, 2)
    const float* __restrict__ boxes,      // (n, G, 5)
    int A, int G,
    double* __restrict__ acc)             // 7 accumulators, stride 16 doubles
{
  __shared__ float4 sBox[G_MAX];  // x0,y0,x1,y1
  __shared__ float2 sAV[G_MAX];   // area, valid
  __shared__ float sRed[4][7];

  const int img = blockIdx.y;
  const int i = blockIdx.x * 256 + threadIdx.x;

  // stage GT boxes for this image into LDS
  const float* gtb = boxes + (size_t)img * G * 5;
  for (int g = threadIdx.x; g < G; g += 256) {
    float x0 = gtb[g * 5 + 0], y0 = gtb[g * 5 + 1];
    float x1 = gtb[g * 5 + 2], y1 = gtb[g * 5 + 3];
    float lb = gtb[g * 5 + 4];
    sBox[g] = make_float4(x0, y0, x1, y1);
    float area = (x1 - x0 + 1.0f) * (y1 - y0 + 1.0f);
    float valid = (lb != -1.0f) ? 1.0f : 0.0f;
    sAV[g] = make_float2(area, valid);
  }
  __syncthreads();

  float t_cls = 0.f, t_bbox = 0.f, t_iou = 0.f, t_num = 0.f;
  float t_npos = 0.f, t_nfg = 0.f, t_ncnt = 0.f;

  if (i < A) {
    const float BBOX_CLIP = 4.1351666f;  // log(1000/16)

    float ax0 = anchors[i * 4 + 0], ay0 = anchors[i * 4 + 1];
    float ax1 = anchors[i * 4 + 2], ay1 = anchors[i * 4 + 3];
    float aw = ax1 - ax0 + 1.0f, ah = ay1 - ay0 + 1.0f;
    float areaa = aw * ah;
    float acx = ax0 + 0.5f * aw, acy = ay0 + 0.5f * ah;

    const float* dp = pred_reg + ((size_t)img * A + i) * 8;
    float d0 = dp[0], d1 = dp[1], d2 = dp[2], d3 = dp[3];
    float d4 = dp[4], d5 = dp[5], d6 = dp[6], d7 = dp[7];

    // decode predicted box 0 (row 2i)
    float p0cx = acx + d0 * aw, p0cy = acy + d1 * ah;
    float p0w = aw * expf(fminf(d2, BBOX_CLIP));
    float p0h = ah * expf(fminf(d3, BBOX_CLIP));
    float b0x0 = p0cx - 0.5f * p0w, b0y0 = p0cy - 0.5f * p0h;
    float b0x1 = p0cx + 0.5f * p0w, b0y1 = p0cy + 0.5f * p0h;
    float area0 = (p0w + 1.0f) * (p0h + 1.0f);

    // decode predicted box 1 (row 2i+1)
    float p1cx = acx + d4 * aw, p1cy = acy + d5 * ah;
    float p1w = aw * expf(fminf(d6, BBOX_CLIP));
    float p1h = ah * expf(fminf(d7, BBOX_CLIP));
    float b1x0 = p1cx - 0.5f * p1w, b1y0 = p1cy - 0.5f * p1h;
    float b1x1 = p1cx + 0.5f * p1w, b1y1 = p1cy + 0.5f * p1h;
    float area1 = (p1w + 1.0f) * (p1h + 1.0f);

    // top-2 of anchor-vs-gt overlap (with -1 for invalid gt)
    float v0 = -2.f, v1 = -2.f;
    int i0 = 0, i1 = 0;
    // max/argmax of decoded-box-0 overlap (keep-masked to 0)
    float amax = -1.f;
    int ai = 0;
    // max/argmax + runner-up of decoded-box-1 overlap
    float bm1 = -1.f, bm2 = -1.f;
    int bi = 0;

    for (int g = 0; g < G; ++g) {
      float4 gb = sBox[g];
      float2 avd = sAV[g];
      // --- raw anchor vs gt (rpn_anchor_target) ---
      {
        float iw = fminf(ax1, gb.z) - fmaxf(ax0, gb.x) + 1.0f;
        float ih = fminf(ay1, gb.w) - fmaxf(ay0, gb.y) + 1.0f;
        float inter = fmaxf(iw, 0.f) * fmaxf(ih, 0.f);
        float uni = areaa + avd.x - inter;
        float iou = inter / fmaxf(uni, 1.0f);
        float ovr = (avd.y != 0.f) ? iou : -1.0f;
        if (ovr > v0) { v1 = v0; i1 = i0; v0 = ovr; i0 = g; }
        else if (ovr > v1) { v1 = ovr; i1 = g; }
      }
      // --- decoded box 0 vs gt (anchor_iou_target a) ---
      {
        float iw = fminf(b0x1, gb.z) - fmaxf(b0x0, gb.x) + 1.0f;
        float ih = fminf(b0y1, gb.w) - fmaxf(b0y0, gb.y) + 1.0f;
        float inter = fmaxf(iw, 0.f) * fmaxf(ih, 0.f);
        float uni = area0 + avd.x - inter;
        float ov = (inter / fmaxf(uni, 1.0f)) * avd.y;
        if (ov > amax) { amax = ov; ai = g; }
      }
      // --- decoded box 1 vs gt (anchor_iou_target b) ---
      {
        float iw = fminf(b1x1, gb.z) - fmaxf(b1x0, gb.x) + 1.0f;
        float ih = fminf(b1y1, gb.w) - fmaxf(b1y0, gb.y) + 1.0f;
        float inter = fmaxf(iw, 0.f) * fmaxf(ih, 0.f);
        float uni = area1 + avd.x - inter;
        float ov = (inter / fmaxf(uni, 1.0f)) * avd.y;
        if (ov > bm1) { bm2 = bm1; bm1 = ov; bi = g; }
        else bm2 = fmaxf(bm2, ov);
      }
    }

    // labels: >=0.5 -> 1, <0.4 -> 0, else -1
    float la  = (v0 >= 0.5f) ? 1.0f : ((v0 < 0.4f) ? 0.0f : -1.0f);
    float lbv = (v1 >= 0.5f) ? 1.0f : ((v1 < 0.4f) ? 0.0f : -1.0f);
    float lab0 = la;
    float lab1 = lbv - (((la == 0.0f) && (lbv != 0.0f)) ? 1.0f : 0.0f);

    // ---- focal classification loss ----
    const float* pc = pred_cls + ((size_t)img * A + i) * 2;
    {
      float p = pc[0];
      if (lab0 != -1.0f) {
        float l = (lab0 == 1.0f)
                      ? 0.25f * (1.0f - p) * (1.0f - p) * logf(p)
                      : 0.75f * p * p * logf(1.0f - p);
        t_cls -= l;
      }
      if (lab0 > 0.f) t_npos += 1.f;
      float q = pc[1];
      if (lab1 != -1.0f) {
        float l = (lab1 == 1.0f)
                      ? 0.25f * (1.0f - q) * (1.0f - q) * logf(q)
                      : 0.75f * q * q * logf(1.0f - q);
        t_cls -= l;
      }
      if (lab1 > 0.f) t_npos += 1.f;
    }

    bool fg0 = (lab0 != 0.0f) && (lab0 != -1.0f);
    bool fg1 = (lab1 != 0.0f) && (lab1 != -1.0f);

    // ---- bbox smooth-L1 vs bbox_transform(anchor, matched gt) ----
    if (fg0) {
      float4 m = sBox[i0];
      float gw = m.z - m.x + 1.0f, gh = m.w - m.y + 1.0f;
      float gcx = m.x + 0.5f * gw, gcy = m.y + 0.5f * gh;
      float t0 = (gcx - acx) / aw, t1v = (gcy - acy) / ah;
      float t2 = logf(gw / aw), t3 = logf(gh / ah);
      t_bbox += huber9(d0 - t0) + huber9(d1 - t1v) + huber9(d2 - t2) + huber9(d3 - t3);
      t_nfg += 1.f;
    }
    if (fg1) {
      float4 m = sBox[i1];
      float gw = m.z - m.x + 1.0f, gh = m.w - m.y + 1.0f;
      float gcx = m.x + 0.5f * gw, gcy = m.y + 0.5f * gh;
      float t0 = (gcx - acx) / aw, t1v = (gcy - acy) / ah;
      float t2 = logf(gw / aw), t3 = logf(gh / ah);
      t_bbox += huber9(d4 - t0) + huber9(d5 - t1v) + huber9(d6 - t2) + huber9(d7 - t3);
      t_nfg += 1.f;
    }

    // ---- IoU L1 loss ----
    {
      const float* ri = rpn_iou + ((size_t)img * A + i) * 2;
      float bval = (ai == bi) ? bm2 : bm1;  // b with b[ai] zeroed, then max
      bval = fmaxf(bval, 0.0f);
      if (fg0) t_iou += fabsf(ri[0] - amax);
      if (fg1) t_iou += fabsf(ri[1] - bval);
    }

    // ---- num softmax loss ----
    {
      int nl = ((lab0 > 0.f) ? 1 : 0) + ((lab1 > 0.f) ? 1 : 0) - 1;
      if (nl != -1) {
        const float* sp = rpn_num + ((size_t)img * A + i) * 2;
        float s0 = sp[0], s1 = sp[1];
        float m = fmaxf(s0, s1);
        float lse = m + logf(expf(s0 - m) + expf(s1 - m));
        float picked = ((nl == 0) ? s0 : s1) - lse;
        t_num -= picked;
        t_ncnt += 1.f;
      }
    }
  }

  // block reduction: wave shuffle -> LDS -> one atomic per scalar per block
  float vals[7] = {t_cls, t_bbox, t_iou, t_num, t_npos, t_nfg, t_ncnt};
  int lane = threadIdx.x & 63;
  int wid = threadIdx.x >> 6;
#pragma unroll
  for (int k = 0; k < 7; ++k) {
    float s = waveSum(vals[k]);
    if (lane == 0) sRed[wid][k] = s;
  }
  __syncthreads();
  if (threadIdx.x < 7) {
    double s = (double)sRed[0][threadIdx.x] + (double)sRed[1][threadIdx.x] +
               (double)sRed[2][threadIdx.x] + (double)sRed[3][threadIdx.x];
    atomicAdd(&acc[threadIdx.x * 16], s);  // stride 16 doubles = 128 B, no line contention
  }
}

__global__ void retina_final(const double* __restrict__ acc, float* __restrict__ out) {
  if (threadIdx.x == 0 && blockIdx.x == 0) {
    double cls = acc[0 * 16], bbox = acc[1 * 16], iou = acc[2 * 16], num = acc[3 * 16];
    double npos = acc[4 * 16], nfg = acc[5 * 16], ncnt = acc[6 * 16];
    double dpos = npos > 1.0 ? npos : 1.0;
    double dfg = nfg > 1.0 ? nfg : 1.0;
    double dcnt = ncnt > 1.0 ? ncnt : 1.0;
    out[0] = (float)(cls / dpos);
    out[1] = (float)(2.0 * bbox / dfg);
    out[2] = (float)(2.0 * iou / dfg);
    out[3] = (float)(num / dcnt);
  }
}

extern "C" void kernel_launch(void* const* d_in, const int* in_sizes, int n_in,
                              void* d_out, int out_size, void* d_ws, size_t ws_size,
                              hipStream_t stream) {
  const float* pred_cls = (const float*)d_in[0];
  const float* rpn_num  = (const float*)d_in[1];
  const float* pred_reg = (const float*)d_in[2];
  const float* anchors  = (const float*)d_in[3];
  const float* rpn_iou  = (const float*)d_in[4];
  const float* boxes    = (const float*)d_in[5];
  // d_in[6] = im_info: unused by the reference math

  int A = in_sizes[3] / 4;
  int n = in_sizes[0] / (2 * A);
  int G = in_sizes[5] / (5 * n);

  double* acc = (double*)d_ws;
  hipMemsetAsync(d_ws, 0, 7 * 16 * sizeof(double), stream);

  dim3 grid((A + 255) / 256, n, 1);
  retina_main<<<grid, dim3(256, 1, 1), 0, stream>>>(pred_cls, rpn_num, pred_reg,
                                                    anchors, rpn_iou, boxes, A, G, acc);
  retina_final<<<1, 64, 0, stream>>>(acc, (float*)d_out);
}

// Round 2
// 220.817 us; speedup vs baseline: 1.2875x; 1.2875x over previous
//
#include <hip/hip_runtime.h>
#include <math.h>

#define G_MAX 512  // LDS capacity for GT boxes; setup uses G=300

__device__ __forceinline__ float waveSum(float v) {
#pragma unroll
  for (int o = 32; o > 0; o >>= 1) v += __shfl_down(v, o, 64);
  return v;
}

// smooth-L1 with sigma=3 (s2=9)
__device__ __forceinline__ float huber9(float x) {
  float ax = fabsf(x);
  return (ax < (1.0f / 9.0f)) ? 4.5f * x * x : ax - (0.5f / 9.0f);
}

// Exact IoU in the reference's op order. g = (x0, y0, x1+1, y1+1), av = (area, valid)
__device__ __forceinline__ float iouExact(float bx0, float by0, float bx1, float by1,
                                          float areab, float4 g, float2 av) {
  float gx1 = g.z - 1.0f, gy1 = g.w - 1.0f;  // exact: x+1 was exact at these magnitudes
  float iw = fminf(bx1, gx1) - fmaxf(bx0, g.x) + 1.0f;
  float ih = fminf(by1, gy1) - fmaxf(by0, g.y) + 1.0f;
  float inter = fmaxf(iw, 0.f) * fmaxf(ih, 0.f);
  float uni = areab + av.x - inter;
  return inter / fmaxf(uni, 1.0f);
}

__global__ __launch_bounds__(256) void retina_main(
    const float* __restrict__ pred_cls,   // (n, A, 2)
    const float* __restrict__ rpn_num,    // (n, A, 2)
    const float* __restrict__ pred_reg,   // (n, A, 8)
    const float* __restrict__ anchors,    // (A, 4)
    const float* __restrict__ rpn_iou,    // (n, A, 2)
    const float* __restrict__ boxes,      // (n, G, 5)
    int A, int G,
    double* __restrict__ acc)             // 7 accumulators, stride 16 doubles
{
  __shared__ float4 sBox[G_MAX];  // x0, y0, x1+1, y1+1
  __shared__ float2 sAV[G_MAX];   // area, valid
  __shared__ float sRed[4][7];

  const int img = blockIdx.y;
  const int i = blockIdx.x * 256 + threadIdx.x;

  // stage GT boxes for this image into LDS
  const float* gtb = boxes + (size_t)img * G * 5;
  for (int g = threadIdx.x; g < G; g += 256) {
    float x0 = gtb[g * 5 + 0], y0 = gtb[g * 5 + 1];
    float x1 = gtb[g * 5 + 2], y1 = gtb[g * 5 + 3];
    float lb = gtb[g * 5 + 4];
    sBox[g] = make_float4(x0, y0, x1 + 1.0f, y1 + 1.0f);
    float area = (x1 - x0 + 1.0f) * (y1 - y0 + 1.0f);
    float valid = (lb != -1.0f) ? 1.0f : 0.0f;
    sAV[g] = make_float2(area, valid);
  }
  __syncthreads();

  float t_cls = 0.f, t_bbox = 0.f, t_iou = 0.f, t_num = 0.f;
  float t_npos = 0.f, t_nfg = 0.f, t_ncnt = 0.f;

  if (i < A) {
    const float BBOX_CLIP = 4.1351666f;  // log(1000/16)

    float ax0 = anchors[i * 4 + 0], ay0 = anchors[i * 4 + 1];
    float ax1 = anchors[i * 4 + 2], ay1 = anchors[i * 4 + 3];
    float aw = ax1 - ax0 + 1.0f, ah = ay1 - ay0 + 1.0f;
    float areaa = aw * ah;
    float acx = ax0 + 0.5f * aw, acy = ay0 + 0.5f * ah;
    float ax1p = ax1 + 1.0f, ay1p = ay1 + 1.0f;

    const float* dp = pred_reg + ((size_t)img * A + i) * 8;
    float d0 = dp[0], d1 = dp[1], d2 = dp[2], d3 = dp[3];
    float d4 = dp[4], d5 = dp[5], d6 = dp[6], d7 = dp[7];
    // hoist small loads so their latency hides under the loop
    const float* pc = pred_cls + ((size_t)img * A + i) * 2;
    float pcv0 = pc[0], pcv1 = pc[1];
    const float* ri = rpn_iou + ((size_t)img * A + i) * 2;
    float riv0 = ri[0], riv1 = ri[1];
    const float* sp = rpn_num + ((size_t)img * A + i) * 2;
    float sn0 = sp[0], sn1 = sp[1];

    // decode predicted box 0 (row 2i)
    float p0cx = acx + d0 * aw, p0cy = acy + d1 * ah;
    float p0w = aw * expf(fminf(d2, BBOX_CLIP));
    float p0h = ah * expf(fminf(d3, BBOX_CLIP));
    float b0x0 = p0cx - 0.5f * p0w, b0y0 = p0cy - 0.5f * p0h;
    float b0x1 = p0cx + 0.5f * p0w, b0y1 = p0cy + 0.5f * p0h;
    float area0 = (b0x1 - b0x0 + 1.0f) * (b0y1 - b0y0 + 1.0f);
    float b0x1p = b0x1 + 1.0f, b0y1p = b0y1 + 1.0f;

    // decode predicted box 1 (row 2i+1)
    float p1cx = acx + d4 * aw, p1cy = acy + d5 * ah;
    float p1w = aw * expf(fminf(d6, BBOX_CLIP));
    float p1h = ah * expf(fminf(d7, BBOX_CLIP));
    float b1x0 = p1cx - 0.5f * p1w, b1y0 = p1cy - 0.5f * p1h;
    float b1x1 = p1cx + 0.5f * p1w, b1y1 = p1cy + 0.5f * p1h;
    float area1 = (b1x1 - b1x0 + 1.0f) * (b1y1 - b1y0 + 1.0f);
    float b1x1p = b1x1 + 1.0f, b1y1p = b1y1 + 1.0f;

    // approx trackers (rcp-based values used ONLY for comparisons; winners
    // are recomputed exactly after the loop)
    float v0a = -2.f, v1a = -2.f;
    int i0 = 0, i1 = 0;
    float amax = -1.f;
    int ai = 0;
    float bm1 = -1.f, bm2 = -1.f;
    int bi = 0, bi2 = 0;

    for (int g = 0; g < G; ++g) {
      float4 gb = sBox[g];   // x0, y0, x1+1, y1+1
      float2 avd = sAV[g];   // area, valid
      bool validg = (avd.y != 0.f);
      // --- raw anchor vs gt (rpn_anchor_target) ---
      {
        float iw = fminf(ax1p, gb.z) - fmaxf(ax0, gb.x);
        float ih = fminf(ay1p, gb.w) - fmaxf(ay0, gb.y);
        float inter = fmaxf(iw, 0.f) * fmaxf(ih, 0.f);
        float uni = areaa + avd.x - inter;           // uni >= 1 always here
        float iou = inter * __builtin_amdgcn_rcpf(uni);
        float ovr = validg ? iou : -1.0f;
        bool c = ovr > v0a;
        bool c2 = ovr > v1a;
        v1a = c ? v0a : (c2 ? ovr : v1a);
        i1 = c ? i0 : (c2 ? g : i1);
        v0a = c ? ovr : v0a;
        i0 = c ? g : i0;
      }
      // --- decoded box 0 vs gt (anchor_iou_target a) ---
      {
        float iw = fminf(b0x1p, gb.z) - fmaxf(b0x0, gb.x);
        float ih = fminf(b0y1p, gb.w) - fmaxf(b0y0, gb.y);
        float inter = fmaxf(iw, 0.f) * fmaxf(ih, 0.f);
        float uni = area0 + avd.x - inter;
        float ov = inter * __builtin_amdgcn_rcpf(uni) * avd.y;
        bool c = ov > amax;
        amax = c ? ov : amax;
        ai = c ? g : ai;
      }
      // --- decoded box 1 vs gt (anchor_iou_target b) ---
      {
        float iw = fminf(b1x1p, gb.z) - fmaxf(b1x0, gb.x);
        float ih = fminf(b1y1p, gb.w) - fmaxf(b1y0, gb.y);
        float inter = fmaxf(iw, 0.f) * fmaxf(ih, 0.f);
        float uni = area1 + avd.x - inter;
        float ov = inter * __builtin_amdgcn_rcpf(uni) * avd.y;
        bool c = ov > bm1;
        bool c2 = ov > bm2;
        bm2 = c ? bm1 : (c2 ? ov : bm2);
        bi2 = c ? bi : (c2 ? g : bi2);
        bm1 = c ? ov : bm1;
        bi = c ? g : bi;
      }
    }

    // ---- exact recompute of winning values (reference op order) ----
    float4 g0 = sBox[i0]; float2 av0 = sAV[i0];
    float v0 = (av0.y != 0.f) ? iouExact(ax0, ay0, ax1, ay1, areaa, g0, av0) : -1.0f;
    float4 g1 = sBox[i1]; float2 av1 = sAV[i1];
    float v1 = (av1.y != 0.f) ? iouExact(ax0, ay0, ax1, ay1, areaa, g1, av1) : -1.0f;
    float4 ga = sBox[ai]; float2 ava = sAV[ai];
    float aval = iouExact(b0x0, b0y0, b0x1, b0y1, area0, ga, ava) * ava.y;
    int bIdx = (ai == bi) ? bi2 : bi;  // b with b[ai] zeroed, then argmax
    float4 gbx = sBox[bIdx]; float2 avb = sAV[bIdx];
    float bval = iouExact(b1x0, b1y0, b1x1, b1y1, area1, gbx, avb) * avb.y;

    // labels: >=0.5 -> 1, <0.4 -> 0, else -1
    float la  = (v0 >= 0.5f) ? 1.0f : ((v0 < 0.4f) ? 0.0f : -1.0f);
    float lbv = (v1 >= 0.5f) ? 1.0f : ((v1 < 0.4f) ? 0.0f : -1.0f);
    float lab0 = la;
    float lab1 = lbv - (((la == 0.0f) && (lbv != 0.0f)) ? 1.0f : 0.0f);

    // ---- focal classification loss ----
    {
      float p = pcv0;
      if (lab0 != -1.0f) {
        float l = (lab0 == 1.0f)
                      ? 0.25f * (1.0f - p) * (1.0f - p) * logf(p)
                      : 0.75f * p * p * logf(1.0f - p);
        t_cls -= l;
      }
      if (lab0 > 0.f) t_npos += 1.f;
      float q = pcv1;
      if (lab1 != -1.0f) {
        float l = (lab1 == 1.0f)
                      ? 0.25f * (1.0f - q) * (1.0f - q) * logf(q)
                      : 0.75f * q * q * logf(1.0f - q);
        t_cls -= l;
      }
      if (lab1 > 0.f) t_npos += 1.f;
    }

    bool fg0 = (lab0 != 0.0f) && (lab0 != -1.0f);
    bool fg1 = (lab1 != 0.0f) && (lab1 != -1.0f);

    // ---- bbox smooth-L1 vs bbox_transform(anchor, matched gt) ----
    if (fg0) {
      float mx1 = g0.z - 1.0f, my1 = g0.w - 1.0f;
      float gw = mx1 - g0.x + 1.0f, gh = my1 - g0.y + 1.0f;
      float gcx = g0.x + 0.5f * gw, gcy = g0.y + 0.5f * gh;
      float t0 = (gcx - acx) / aw, t1v = (gcy - acy) / ah;
      float t2 = logf(gw / aw), t3 = logf(gh / ah);
      t_bbox += huber9(d0 - t0) + huber9(d1 - t1v) + huber9(d2 - t2) + huber9(d3 - t3);
      t_nfg += 1.f;
    }
    if (fg1) {
      float mx1 = g1.z - 1.0f, my1 = g1.w - 1.0f;
      float gw = mx1 - g1.x + 1.0f, gh = my1 - g1.y + 1.0f;
      float gcx = g1.x + 0.5f * gw, gcy = g1.y + 0.5f * gh;
      float t0 = (gcx - acx) / aw, t1v = (gcy - acy) / ah;
      float t2 = logf(gw / aw), t3 = logf(gh / ah);
      t_bbox += huber9(d4 - t0) + huber9(d5 - t1v) + huber9(d6 - t2) + huber9(d7 - t3);
      t_nfg += 1.f;
    }

    // ---- IoU L1 loss ----
    {
      if (fg0) t_iou += fabsf(riv0 - aval);
      if (fg1) t_iou += fabsf(riv1 - fmaxf(bval, 0.0f));
    }

    // ---- num softmax loss ----
    {
      int nl = ((lab0 > 0.f) ? 1 : 0) + ((lab1 > 0.f) ? 1 : 0) - 1;
      if (nl != -1) {
        float m = fmaxf(sn0, sn1);
        float lse = m + logf(expf(sn0 - m) + expf(sn1 - m));
        float picked = ((nl == 0) ? sn0 : sn1) - lse;
        t_num -= picked;
        t_ncnt += 1.f;
      }
    }
  }

  // block reduction: wave shuffle -> LDS -> one atomic per scalar per block
  float vals[7] = {t_cls, t_bbox, t_iou, t_num, t_npos, t_nfg, t_ncnt};
  int lane = threadIdx.x & 63;
  int wid = threadIdx.x >> 6;
#pragma unroll
  for (int k = 0; k < 7; ++k) {
    float s = waveSum(vals[k]);
    if (lane == 0) sRed[wid][k] = s;
  }
  __syncthreads();
  if (threadIdx.x < 7) {
    double s = (double)sRed[0][threadIdx.x] + (double)sRed[1][threadIdx.x] +
               (double)sRed[2][threadIdx.x] + (double)sRed[3][threadIdx.x];
    atomicAdd(&acc[threadIdx.x * 16], s);  // stride 16 doubles = 128 B, no line contention
  }
}

__global__ void retina_final(const double* __restrict__ acc, float* __restrict__ out) {
  if (threadIdx.x == 0 && blockIdx.x == 0) {
    double cls = acc[0 * 16], bbox = acc[1 * 16], iou = acc[2 * 16], num = acc[3 * 16];
    double npos = acc[4 * 16], nfg = acc[5 * 16], ncnt = acc[6 * 16];
    double dpos = npos > 1.0 ? npos : 1.0;
    double dfg = nfg > 1.0 ? nfg : 1.0;
    double dcnt = ncnt > 1.0 ? ncnt : 1.0;
    out[0] = (float)(cls / dpos);
    out[1] = (float)(2.0 * bbox / dfg);
    out[2] = (float)(2.0 * iou / dfg);
    out[3] = (float)(num / dcnt);
  }
}

extern "C" void kernel_launch(void* const* d_in, const int* in_sizes, int n_in,
                              void* d_out, int out_size, void* d_ws, size_t ws_size,
                              hipStream_t stream) {
  const float* pred_cls = (const float*)d_in[0];
  const float* rpn_num  = (const float*)d_in[1];
  const float* pred_reg = (const float*)d_in[2];
  const float* anchors  = (const float*)d_in[3];
  const float* rpn_iou  = (const float*)d_in[4];
  const float* boxes    = (const float*)d_in[5];
  // d_in[6] = im_info: unused by the reference math

  int A = in_sizes[3] / 4;
  int n = in_sizes[0] / (2 * A);
  int G = in_sizes[5] / (5 * n);

  double* acc = (double*)d_ws;
  hipMemsetAsync(d_ws, 0, 7 * 16 * sizeof(double), stream);

  dim3 grid((A + 255) / 256, n, 1);
  retina_main<<<grid, dim3(256, 1, 1), 0, stream>>>(pred_cls, rpn_num, pred_reg,
                                                    anchors, rpn_iou, boxes, A, G, acc);
  retina_final<<<1, 64, 0, stream>>>(acc, (float*)d_out);
}

// Round 3
// 193.228 us; speedup vs baseline: 1.4714x; 1.1428x over previous
//
#include <hip/hip_runtime.h>
#include <math.h>

#define G_MAX 512   // LDS capacity for GT boxes; setup uses G=300
#define SPLIT 4     // threads per anchor (g-loop split)

__device__ __forceinline__ float waveSum(float v) {
#pragma unroll
  for (int o = 32; o > 0; o >>= 1) v += __shfl_down(v, o, 64);
  return v;
}

// smooth-L1 with sigma=3 (s2=9)
__device__ __forceinline__ float huber9(float x) {
  float ax = fabsf(x);
  return (ax < (1.0f / 9.0f)) ? 4.5f * x * x : ax - (0.5f / 9.0f);
}

// Exact IoU in the reference's op order. g = (x0, y0, x1+1, y1+1)
__device__ __forceinline__ float iouExact(float bx0, float by0, float bx1, float by1,
                                          float areab, float4 g, float areag) {
  float gx1 = g.z - 1.0f, gy1 = g.w - 1.0f;  // exact inverse of the staged +1
  float iw = fminf(bx1, gx1) - fmaxf(bx0, g.x) + 1.0f;
  float ih = fminf(by1, gy1) - fmaxf(by0, g.y) + 1.0f;
  float inter = fmaxf(iw, 0.f) * fmaxf(ih, 0.f);
  float uni = areab + areag - inter;
  return inter / fmaxf(uni, 1.0f);
}

// Comparison-domain packed IoU: bits(iou+2) with low 9 mantissa bits = 511-g.
// Positive floats compare identically as uints; complemented index makes
// quantized ties resolve to the SMALLEST g (jax top_k stable semantics).
// Invalid/dummy boxes carry area=1e30 so iou ~ 1e-30 quantizes to exactly 2.0.
__device__ __forceinline__ uint32_t packIoU(float x0, float y0, float x1p, float y1p,
                                            float area, float4 gb, float ga,
                                            uint32_t gcomp) {
  float iw = fminf(x1p, gb.z) - fmaxf(x0, gb.x);
  float ih = fminf(y1p, gb.w) - fmaxf(y0, gb.y);
  float inter = fmaxf(iw, 0.f) * fmaxf(ih, 0.f);
  float uni = area + ga - inter;  // >= 1 always (areas >= 1)
  float r = __builtin_amdgcn_rcpf(uni);
  float v = fmaf(inter, r, 2.0f);
  return (__float_as_uint(v) & 0xFFFFFE00u) | gcomp;
}

__global__ __launch_bounds__(256) void retina_main(
    const float* __restrict__ pred_cls,   // (n, A, 2)
    const float* __restrict__ rpn_num,    // (n, A, 2)
    const float* __restrict__ pred_reg,   // (n, A, 8)
    const float* __restrict__ anchors,    // (A, 4)
    const float* __restrict__ rpn_iou,    // (n, A, 2)
    const float* __restrict__ boxes,      // (n, G, 5)
    int A, int G,
    double* __restrict__ acc)             // 7 accumulators, stride 16 doubles
{
  __shared__ float4 sBox[G_MAX];  // x0, y0, x1+1, y1+1
  __shared__ float sA[G_MAX];     // area (1e30 for invalid/dummy)
  __shared__ float sRed[4][7];

  const int img = blockIdx.y;
  const int seg = threadIdx.x & (SPLIT - 1);
  const int al  = threadIdx.x >> 2;          // anchor-local 0..63
  const int i   = blockIdx.x * 64 + al;
  const int ic  = (i < A) ? i : (A - 1);

  const int len  = (G + SPLIT - 1) / SPLIT;
  const int padG = len * SPLIT;              // <= G_MAX

  // stage GT boxes (pad range with inert dummies: area=1e30 -> packs to 2.0)
  const float* gtb = boxes + (size_t)img * G * 5;
  for (int g = threadIdx.x; g < padG; g += 256) {
    if (g < G) {
      float x0 = gtb[g * 5 + 0], y0 = gtb[g * 5 + 1];
      float x1 = gtb[g * 5 + 2], y1 = gtb[g * 5 + 3];
      float lb = gtb[g * 5 + 4];
      sBox[g] = make_float4(x0, y0, x1 + 1.0f, y1 + 1.0f);
      sA[g] = (lb != -1.0f) ? (x1 - x0 + 1.0f) * (y1 - y0 + 1.0f) : 1e30f;
    } else {
      sBox[g] = make_float4(0.f, 0.f, 1.f, 1.f);
      sA[g] = 1e30f;
    }
  }
  __syncthreads();

  float t_cls = 0.f, t_bbox = 0.f, t_iou = 0.f, t_num = 0.f;
  float t_npos = 0.f, t_nfg = 0.f, t_ncnt = 0.f;

  const float BBOX_CLIP = 4.1351666f;  // log(1000/16)

  // per-anchor data (4 lanes share one anchor; redundant loads hit L1)
  float ax0 = anchors[ic * 4 + 0], ay0 = anchors[ic * 4 + 1];
  float ax1 = anchors[ic * 4 + 2], ay1 = anchors[ic * 4 + 3];
  float aw = ax1 - ax0 + 1.0f, ah = ay1 - ay0 + 1.0f;
  float areaa = aw * ah;
  float acx = ax0 + 0.5f * aw, acy = ay0 + 0.5f * ah;
  float ax1p = ax1 + 1.0f, ay1p = ay1 + 1.0f;

  const float* dp = pred_reg + ((size_t)img * A + ic) * 8;
  float d0 = dp[0], d1 = dp[1], d2 = dp[2], d3 = dp[3];
  float d4 = dp[4], d5 = dp[5], d6 = dp[6], d7 = dp[7];

  // epilogue-only inputs: issue early (exec-masked to seg 0) to hide latency
  float pcv0 = 0.f, pcv1 = 0.f, riv0 = 0.f, riv1 = 0.f, sn0 = 0.f, sn1 = 0.f;
  if (seg == 0) {
    const float* pc = pred_cls + ((size_t)img * A + ic) * 2;
    pcv0 = pc[0]; pcv1 = pc[1];
    const float* ri = rpn_iou + ((size_t)img * A + ic) * 2;
    riv0 = ri[0]; riv1 = ri[1];
    const float* sp = rpn_num + ((size_t)img * A + ic) * 2;
    sn0 = sp[0]; sn1 = sp[1];
  }

  // decode predicted boxes
  float p0cx = acx + d0 * aw, p0cy = acy + d1 * ah;
  float p0w = aw * expf(fminf(d2, BBOX_CLIP));
  float p0h = ah * expf(fminf(d3, BBOX_CLIP));
  float b0x0 = p0cx - 0.5f * p0w, b0y0 = p0cy - 0.5f * p0h;
  float b0x1 = p0cx + 0.5f * p0w, b0y1 = p0cy + 0.5f * p0h;
  float area0 = (b0x1 - b0x0 + 1.0f) * (b0y1 - b0y0 + 1.0f);
  float b0x1p = b0x1 + 1.0f, b0y1p = b0y1 + 1.0f;

  float p1cx = acx + d4 * aw, p1cy = acy + d5 * ah;
  float p1w = aw * expf(fminf(d6, BBOX_CLIP));
  float p1h = ah * expf(fminf(d7, BBOX_CLIP));
  float b1x0 = p1cx - 0.5f * p1w, b1y0 = p1cy - 0.5f * p1h;
  float b1x1 = p1cx + 0.5f * p1w, b1y1 = p1cy + 0.5f * p1h;
  float area1 = (b1x1 - b1x0 + 1.0f) * (b1y1 - b1y0 + 1.0f);
  float b1x1p = b1x1 + 1.0f, b1y1p = b1y1 + 1.0f;

  // packed trackers (merge-associative)
  uint32_t an1 = 0u, an2 = 0u;   // anchor-vs-gt top-2
  uint32_t am  = 0u;             // decoded box 0 max
  uint32_t bm1 = 0u, bm2 = 0u;   // decoded box 1 top-2

  int g = seg * len;
  for (int t = 0; t < len; ++t, ++g) {
    float4 gb = sBox[g];
    float ga = sA[g];
    uint32_t gcomp = 511u - (uint32_t)g;
    {
      uint32_t p = packIoU(ax0, ay0, ax1p, ay1p, areaa, gb, ga, gcomp);
      uint32_t lo = min(p, an1);
      an1 = max(an1, p);
      an2 = max(an2, lo);
    }
    {
      uint32_t p = packIoU(b0x0, b0y0, b0x1p, b0y1p, area0, gb, ga, gcomp);
      am = max(am, p);
    }
    {
      uint32_t p = packIoU(b1x0, b1y0, b1x1p, b1y1p, area1, gb, ga, gcomp);
      uint32_t lo = min(p, bm1);
      bm1 = max(bm1, p);
      bm2 = max(bm2, lo);
    }
  }

  // butterfly merge across the 4 lanes of this anchor
#pragma unroll
  for (int m = 1; m <= 2; m <<= 1) {
    uint32_t o1 = (uint32_t)__shfl_xor((int)an1, m, 64);
    uint32_t o2 = (uint32_t)__shfl_xor((int)an2, m, 64);
    uint32_t lo = min(an1, o1);
    an1 = max(an1, o1);
    an2 = max(max(an2, o2), lo);

    am = max(am, (uint32_t)__shfl_xor((int)am, m, 64));

    uint32_t q1 = (uint32_t)__shfl_xor((int)bm1, m, 64);
    uint32_t q2 = (uint32_t)__shfl_xor((int)bm2, m, 64);
    uint32_t lob = min(bm1, q1);
    bm1 = max(bm1, q1);
    bm2 = max(max(bm2, q2), lob);
  }

  if (seg == 0 && i < A) {
    // extract winning indices
    int i0 = 511 - (int)(an1 & 0x1FFu); i0 = (i0 < G) ? i0 : (G - 1); i0 = i0 < 0 ? 0 : i0;
    int i1 = 511 - (int)(an2 & 0x1FFu); i1 = (i1 < G) ? i1 : (G - 1); i1 = i1 < 0 ? 0 : i1;
    int ai = 511 - (int)(am  & 0x1FFu); ai = (ai < G) ? ai : (G - 1); ai = ai < 0 ? 0 : ai;
    int bi = 511 - (int)(bm1 & 0x1FFu); bi = (bi < G) ? bi : (G - 1); bi = bi < 0 ? 0 : bi;
    int bi2= 511 - (int)(bm2 & 0x1FFu); bi2= (bi2< G) ? bi2: (G - 1); bi2= bi2< 0 ? 0 : bi2;

    // exact recompute of winning values (reference op order, explicit validity)
    float4 g0 = sBox[i0]; float a0 = sA[i0]; bool val0 = a0 < 1e29f;
    float v0 = val0 ? iouExact(ax0, ay0, ax1, ay1, areaa, g0, a0) : -1.0f;
    float4 g1 = sBox[i1]; float a1 = sA[i1]; bool val1 = a1 < 1e29f;
    float v1 = val1 ? iouExact(ax0, ay0, ax1, ay1, areaa, g1, a1) : -1.0f;
    float4 ga4 = sBox[ai]; float aav = sA[ai];
    float aval = (aav < 1e29f) ? iouExact(b0x0, b0y0, b0x1, b0y1, area0, ga4, aav) : 0.0f;
    int bIdx = (ai == bi) ? bi2 : bi;  // b with b[ai] zeroed, then argmax
    float4 gb4 = sBox[bIdx]; float abv = sA[bIdx];
    float bval = (abv < 1e29f) ? iouExact(b1x0, b1y0, b1x1, b1y1, area1, gb4, abv) : 0.0f;

    // labels: >=0.5 -> 1, <0.4 -> 0, else -1
    float la  = (v0 >= 0.5f) ? 1.0f : ((v0 < 0.4f) ? 0.0f : -1.0f);
    float lbv = (v1 >= 0.5f) ? 1.0f : ((v1 < 0.4f) ? 0.0f : -1.0f);
    float lab0 = la;
    float lab1 = lbv - (((la == 0.0f) && (lbv != 0.0f)) ? 1.0f : 0.0f);

    // ---- focal classification loss ----
    {
      float p = pcv0;
      if (lab0 != -1.0f) {
        float l = (lab0 == 1.0f)
                      ? 0.25f * (1.0f - p) * (1.0f - p) * logf(p)
                      : 0.75f * p * p * logf(1.0f - p);
        t_cls -= l;
      }
      if (lab0 > 0.f) t_npos += 1.f;
      float q = pcv1;
      if (lab1 != -1.0f) {
        float l = (lab1 == 1.0f)
                      ? 0.25f * (1.0f - q) * (1.0f - q) * logf(q)
                      : 0.75f * q * q * logf(1.0f - q);
        t_cls -= l;
      }
      if (lab1 > 0.f) t_npos += 1.f;
    }

    bool fg0 = (lab0 != 0.0f) && (lab0 != -1.0f);
    bool fg1 = (lab1 != 0.0f) && (lab1 != -1.0f);

    // ---- bbox smooth-L1 vs bbox_transform(anchor, matched gt) ----
    if (fg0) {
      float mx1 = g0.z - 1.0f, my1 = g0.w - 1.0f;
      float gw = mx1 - g0.x + 1.0f, gh = my1 - g0.y + 1.0f;
      float gcx = g0.x + 0.5f * gw, gcy = g0.y + 0.5f * gh;
      float t0 = (gcx - acx) / aw, t1v = (gcy - acy) / ah;
      float t2 = logf(gw / aw), t3 = logf(gh / ah);
      t_bbox += huber9(d0 - t0) + huber9(d1 - t1v) + huber9(d2 - t2) + huber9(d3 - t3);
      t_nfg += 1.f;
    }
    if (fg1) {
      float mx1 = g1.z - 1.0f, my1 = g1.w - 1.0f;
      float gw = mx1 - g1.x + 1.0f, gh = my1 - g1.y + 1.0f;
      float gcx = g1.x + 0.5f * gw, gcy = g1.y + 0.5f * gh;
      float t0 = (gcx - acx) / aw, t1v = (gcy - acy) / ah;
      float t2 = logf(gw / aw), t3 = logf(gh / ah);
      t_bbox += huber9(d4 - t0) + huber9(d5 - t1v) + huber9(d6 - t2) + huber9(d7 - t3);
      t_nfg += 1.f;
    }

    // ---- IoU L1 loss ----
    if (fg0) t_iou += fabsf(riv0 - aval);
    if (fg1) t_iou += fabsf(riv1 - fmaxf(bval, 0.0f));

    // ---- num softmax loss ----
    {
      int nl = ((lab0 > 0.f) ? 1 : 0) + ((lab1 > 0.f) ? 1 : 0) - 1;
      if (nl != -1) {
        float m = fmaxf(sn0, sn1);
        float lse = m + logf(expf(sn0 - m) + expf(sn1 - m));
        float picked = ((nl == 0) ? sn0 : sn1) - lse;
        t_num -= picked;
        t_ncnt += 1.f;
      }
    }
  }

  // block reduction: wave shuffle -> LDS -> one atomic per scalar per block
  float vals[7] = {t_cls, t_bbox, t_iou, t_num, t_npos, t_nfg, t_ncnt};
  int lane = threadIdx.x & 63;
  int wid = threadIdx.x >> 6;
#pragma unroll
  for (int k = 0; k < 7; ++k) {
    float s = waveSum(vals[k]);
    if (lane == 0) sRed[wid][k] = s;
  }
  __syncthreads();
  if (threadIdx.x < 7) {
    double s = (double)sRed[0][threadIdx.x] + (double)sRed[1][threadIdx.x] +
               (double)sRed[2][threadIdx.x] + (double)sRed[3][threadIdx.x];
    atomicAdd(&acc[threadIdx.x * 16], s);  // stride 16 doubles = 128 B apart
  }
}

__global__ void retina_final(const double* __restrict__ acc, float* __restrict__ out) {
  if (threadIdx.x == 0 && blockIdx.x == 0) {
    double cls = acc[0 * 16], bbox = acc[1 * 16], iou = acc[2 * 16], num = acc[3 * 16];
    double npos = acc[4 * 16], nfg = acc[5 * 16], ncnt = acc[6 * 16];
    double dpos = npos > 1.0 ? npos : 1.0;
    double dfg = nfg > 1.0 ? nfg : 1.0;
    double dcnt = ncnt > 1.0 ? ncnt : 1.0;
    out[0] = (float)(cls / dpos);
    out[1] = (float)(2.0 * bbox / dfg);
    out[2] = (float)(2.0 * iou / dfg);
    out[3] = (float)(num / dcnt);
  }
}

extern "C" void kernel_launch(void* const* d_in, const int* in_sizes, int n_in,
                              void* d_out, int out_size, void* d_ws, size_t ws_size,
                              hipStream_t stream) {
  const float* pred_cls = (const float*)d_in[0];
  const float* rpn_num  = (const float*)d_in[1];
  const float* pred_reg = (const float*)d_in[2];
  const float* anchors  = (const float*)d_in[3];
  const float* rpn_iou  = (const float*)d_in[4];
  const float* boxes    = (const float*)d_in[5];
  // d_in[6] = im_info: unused by the reference math

  int A = in_sizes[3] / 4;
  int n = in_sizes[0] / (2 * A);
  int G = in_sizes[5] / (5 * n);

  double* acc = (double*)d_ws;
  hipMemsetAsync(d_ws, 0, 7 * 16 * sizeof(double), stream);

  dim3 grid((A + 63) / 64, n, 1);  // 64 anchors/block x SPLIT=4 lanes
  retina_main<<<grid, dim3(256, 1, 1), 0, stream>>>(pred_cls, rpn_num, pred_reg,
                                                    anchors, rpn_iou, boxes, A, G, acc);
  retina_final<<<1, 64, 0, stream>>>(acc, (float*)d_out);
}

// Round 5
// 185.878 us; speedup vs baseline: 1.5295x; 1.0395x over previous
//
#include <hip/hip_runtime.h>
#include <math.h>

#define G_MAX 512   // LDS capacity for GT boxes; setup uses G=300
#define SPLIT 4     // threads per anchor (g-loop split)

__device__ __forceinline__ float waveSum(float v) {
#pragma unroll
  for (int o = 32; o > 0; o >>= 1) v += __shfl_down(v, o, 64);
  return v;
}

// smooth-L1 with sigma=3 (s2=9)
__device__ __forceinline__ float huber9(float x) {
  float ax = fabsf(x);
  return (ax < (1.0f / 9.0f)) ? 4.5f * x * x : ax - (0.5f / 9.0f);
}

// Exact IoU in the reference's op order. g = (x0, y0, x1+1, y1+1)
__device__ __forceinline__ float iouExact(float bx0, float by0, float bx1, float by1,
                                          float areab, float4 g, float areag) {
  float gx1 = g.z - 1.0f, gy1 = g.w - 1.0f;  // exact inverse of the staged +1
  float iw = fminf(bx1, gx1) - fmaxf(bx0, g.x) + 1.0f;
  float ih = fminf(by1, gy1) - fmaxf(by0, g.y) + 1.0f;
  float inter = fmaxf(iw, 0.f) * fmaxf(ih, 0.f);
  float uni = areab + areag - inter;
  return inter / fmaxf(uni, 1.0f);
}

// Inverse comparison key: key = (areaB+areaG)*rcp(inter). Since
// iou = inter/(S-inter) = f(inter/S) with f monotone increasing and inter/S<1,
// argmax iou == argmin key. inter==0 -> key=+inf (worst). Low 9 mantissa bits
// replaced by plain g: uint-min ties resolve to SMALLEST g (jax stable
// top_k/argmax). Invalid gts carry area=1e30 -> huge key, ranking below all
// meaningfully-overlapping valid gts; divergences from the reference ordering
// occur only among {zero-overlap, invalid} candidates, and every such case
// yields label 0 / masked values identically (winners recomputed exactly with
// explicit validity masks after the loop).
__device__ __forceinline__ uint32_t packKey(float x0, float y0, float x1p, float y1p,
                                            float area, float4 gb, float ga,
                                            uint32_t g) {
  float iw = fminf(x1p, gb.z) - fmaxf(x0, gb.x);
  float ih = fminf(y1p, gb.w) - fmaxf(y0, gb.y);
  float inter = fmaxf(iw, 0.f) * fmaxf(ih, 0.f);
  float key = (area + ga) * __builtin_amdgcn_rcpf(inter);
  return (__float_as_uint(key) & 0xFFFFFE00u) | g;
}

__global__ __launch_bounds__(256) void retina_main(
    const float* __restrict__ pred_cls,   // (n, A, 2)
    const float* __restrict__ rpn_num,    // (n, A, 2)
    const float* __restrict__ pred_reg,   // (n, A, 8)
    const float* __restrict__ anchors,    // (A, 4)
    const float* __restrict__ rpn_iou,    // (n, A, 2)
    const float* __restrict__ boxes,      // (n, G, 5)
    int A, int G, int totalBlocks,
    double* __restrict__ acc,             // 7 accumulators, stride 16 doubles
    unsigned int* __restrict__ cnt,       // ticket counter (zeroed)
    float* __restrict__ out)              // 4 floats
{
  __shared__ float4 sBox[G_MAX];  // x0, y0, x1+1, y1+1
  __shared__ float sA[G_MAX];     // area (1e30 for invalid/dummy)
  __shared__ float sRed[4][7];
  __shared__ int sLast;

  const int img = blockIdx.y;
  const int seg = threadIdx.x & (SPLIT - 1);
  const int al  = threadIdx.x >> 2;          // anchor-local 0..63
  const int i   = blockIdx.x * 64 + al;
  const int ic  = (i < A) ? i : (A - 1);

  const int len  = (G + SPLIT - 1) / SPLIT;
  const int padG = len * SPLIT;              // <= G_MAX

  // stage GT boxes (pad range with inert dummies: area=1e30)
  const float* gtb = boxes + (size_t)img * G * 5;
  for (int g = threadIdx.x; g < padG; g += 256) {
    if (g < G) {
      float x0 = gtb[g * 5 + 0], y0 = gtb[g * 5 + 1];
      float x1 = gtb[g * 5 + 2], y1 = gtb[g * 5 + 3];
      float lb = gtb[g * 5 + 4];
      sBox[g] = make_float4(x0, y0, x1 + 1.0f, y1 + 1.0f);
      sA[g] = (lb != -1.0f) ? (x1 - x0 + 1.0f) * (y1 - y0 + 1.0f) : 1e30f;
    } else {
      sBox[g] = make_float4(0.f, 0.f, 1.f, 1.f);
      sA[g] = 1e30f;
    }
  }
  __syncthreads();

  float t_cls = 0.f, t_bbox = 0.f, t_iou = 0.f, t_num = 0.f;
  float t_npos = 0.f, t_nfg = 0.f, t_ncnt = 0.f;

  const float BBOX_CLIP = 4.1351666f;  // log(1000/16)

  // per-anchor data (4 lanes share one anchor; redundant loads hit L1)
  float ax0 = anchors[ic * 4 + 0], ay0 = anchors[ic * 4 + 1];
  float ax1 = anchors[ic * 4 + 2], ay1 = anchors[ic * 4 + 3];
  float aw = ax1 - ax0 + 1.0f, ah = ay1 - ay0 + 1.0f;
  float areaa = aw * ah;
  float acx = ax0 + 0.5f * aw, acy = ay0 + 0.5f * ah;
  float ax1p = ax1 + 1.0f, ay1p = ay1 + 1.0f;

  const float* dp = pred_reg + ((size_t)img * A + ic) * 8;
  float d0 = dp[0], d1 = dp[1], d2 = dp[2], d3 = dp[3];
  float d4 = dp[4], d5 = dp[5], d6 = dp[6], d7 = dp[7];

  // epilogue-only inputs: issue early (exec-masked to seg 0) to hide latency
  float pcv0 = 0.f, pcv1 = 0.f, riv0 = 0.f, riv1 = 0.f, sn0 = 0.f, sn1 = 0.f;
  if (seg == 0) {
    const float* pc = pred_cls + ((size_t)img * A + ic) * 2;
    pcv0 = pc[0]; pcv1 = pc[1];
    const float* ri = rpn_iou + ((size_t)img * A + ic) * 2;
    riv0 = ri[0]; riv1 = ri[1];
    const float* sp = rpn_num + ((size_t)img * A + ic) * 2;
    sn0 = sp[0]; sn1 = sp[1];
  }

  // decode predicted boxes
  float p0cx = acx + d0 * aw, p0cy = acy + d1 * ah;
  float p0w = aw * expf(fminf(d2, BBOX_CLIP));
  float p0h = ah * expf(fminf(d3, BBOX_CLIP));
  float b0x0 = p0cx - 0.5f * p0w, b0y0 = p0cy - 0.5f * p0h;
  float b0x1 = p0cx + 0.5f * p0w, b0y1 = p0cy + 0.5f * p0h;
  float area0 = (b0x1 - b0x0 + 1.0f) * (b0y1 - b0y0 + 1.0f);
  float b0x1p = b0x1 + 1.0f, b0y1p = b0y1 + 1.0f;

  float p1cx = acx + d4 * aw, p1cy = acy + d5 * ah;
  float p1w = aw * expf(fminf(d6, BBOX_CLIP));
  float p1h = ah * expf(fminf(d7, BBOX_CLIP));
  float b1x0 = p1cx - 0.5f * p1w, b1y0 = p1cy - 0.5f * p1h;
  float b1x1 = p1cx + 0.5f * p1w, b1y1 = p1cy + 0.5f * p1h;
  float area1 = (b1x1 - b1x0 + 1.0f) * (b1y1 - b1y0 + 1.0f);
  float b1x1p = b1x1 + 1.0f, b1y1p = b1y1 + 1.0f;

  // min-trackers over inverse keys (merge-associative)
  uint32_t an1 = 0xFFFFFFFFu, an2 = 0xFFFFFFFFu;   // anchor-vs-gt best/2nd
  uint32_t am  = 0xFFFFFFFFu;                      // decoded box 0 best
  uint32_t bk1 = 0xFFFFFFFFu, bk2 = 0xFFFFFFFFu;   // decoded box 1 best/2nd

  int g = seg * len;
#pragma unroll 5
  for (int t = 0; t < len; ++t, ++g) {
    float4 gb = sBox[g];
    float ga = sA[g];
    uint32_t gu = (uint32_t)g;
    {
      uint32_t p = packKey(ax0, ay0, ax1p, ay1p, areaa, gb, ga, gu);
      uint32_t hi = max(p, an1);
      an1 = min(an1, p);
      an2 = min(an2, hi);
    }
    {
      uint32_t p = packKey(b0x0, b0y0, b0x1p, b0y1p, area0, gb, ga, gu);
      am = min(am, p);
    }
    {
      uint32_t p = packKey(b1x0, b1y0, b1x1p, b1y1p, area1, gb, ga, gu);
      uint32_t hi = max(p, bk1);
      bk1 = min(bk1, p);
      bk2 = min(bk2, hi);
    }
  }

  // butterfly merge across the 4 lanes of this anchor
#pragma unroll
  for (int m = 1; m <= 2; m <<= 1) {
    uint32_t o1 = (uint32_t)__shfl_xor((int)an1, m, 64);
    uint32_t o2 = (uint32_t)__shfl_xor((int)an2, m, 64);
    uint32_t hi = max(an1, o1);
    an1 = min(an1, o1);
    an2 = min(min(an2, o2), hi);

    am = min(am, (uint32_t)__shfl_xor((int)am, m, 64));

    uint32_t q1 = (uint32_t)__shfl_xor((int)bk1, m, 64);
    uint32_t q2 = (uint32_t)__shfl_xor((int)bk2, m, 64);
    uint32_t hib = max(bk1, q1);
    bk1 = min(bk1, q1);
    bk2 = min(min(bk2, q2), hib);
  }

  if (seg == 0 && i < A) {
    // winning indices (plain low bits; always < padG, dummies handled by sA)
    int i0 = (int)(an1 & 0x1FFu);
    int i1 = (int)(an2 & 0x1FFu);
    int ai = (int)(am  & 0x1FFu);
    int bi = (int)(bk1 & 0x1FFu);
    int bi2= (int)(bk2 & 0x1FFu);

    // exact recompute of winning values (reference op order, explicit validity)
    float4 g0 = sBox[i0]; float a0 = sA[i0]; bool val0 = a0 < 1e29f;
    float v0 = val0 ? iouExact(ax0, ay0, ax1, ay1, areaa, g0, a0) : -1.0f;
    float4 g1 = sBox[i1]; float a1 = sA[i1]; bool val1 = a1 < 1e29f;
    float v1 = val1 ? iouExact(ax0, ay0, ax1, ay1, areaa, g1, a1) : -1.0f;
    float4 ga4 = sBox[ai]; float aav = sA[ai];
    float aval = (aav < 1e29f) ? iouExact(b0x0, b0y0, b0x1, b0y1, area0, ga4, aav) : 0.0f;
    int bIdx = (ai == bi) ? bi2 : bi;  // b with b[ai] zeroed, then argmax
    float4 gb4 = sBox[bIdx]; float abv = sA[bIdx];
    float bval = (abv < 1e29f) ? iouExact(b1x0, b1y0, b1x1, b1y1, area1, gb4, abv) : 0.0f;

    // labels: >=0.5 -> 1, <0.4 -> 0, else -1
    float la  = (v0 >= 0.5f) ? 1.0f : ((v0 < 0.4f) ? 0.0f : -1.0f);
    float lbv = (v1 >= 0.5f) ? 1.0f : ((v1 < 0.4f) ? 0.0f : -1.0f);
    float lab0 = la;
    float lab1 = lbv - (((la == 0.0f) && (lbv != 0.0f)) ? 1.0f : 0.0f);

    // ---- focal classification loss ----
    {
      float p = pcv0;
      if (lab0 != -1.0f) {
        float l = (lab0 == 1.0f)
                      ? 0.25f * (1.0f - p) * (1.0f - p) * logf(p)
                      : 0.75f * p * p * logf(1.0f - p);
        t_cls -= l;
      }
      if (lab0 > 0.f) t_npos += 1.f;
      float q = pcv1;
      if (lab1 != -1.0f) {
        float l = (lab1 == 1.0f)
                      ? 0.25f * (1.0f - q) * (1.0f - q) * logf(q)
                      : 0.75f * q * q * logf(1.0f - q);
        t_cls -= l;
      }
      if (lab1 > 0.f) t_npos += 1.f;
    }

    bool fg0 = (lab0 != 0.0f) && (lab0 != -1.0f);
    bool fg1 = (lab1 != 0.0f) && (lab1 != -1.0f);

    // fast reciprocals for the bbox-target divides (rel err ~1e-7, harmless)
    float raw = __builtin_amdgcn_rcpf(aw), rah = __builtin_amdgcn_rcpf(ah);

    // ---- bbox smooth-L1 vs bbox_transform(anchor, matched gt) ----
    if (fg0) {
      float mx1 = g0.z - 1.0f, my1 = g0.w - 1.0f;
      float gw = mx1 - g0.x + 1.0f, gh = my1 - g0.y + 1.0f;
      float gcx = g0.x + 0.5f * gw, gcy = g0.y + 0.5f * gh;
      float t0 = (gcx - acx) * raw, t1v = (gcy - acy) * rah;
      float t2 = logf(gw * raw), t3 = logf(gh * rah);
      t_bbox += huber9(d0 - t0) + huber9(d1 - t1v) + huber9(d2 - t2) + huber9(d3 - t3);
      t_nfg += 1.f;
    }
    if (fg1) {
      float mx1 = g1.z - 1.0f, my1 = g1.w - 1.0f;
      float gw = mx1 - g1.x + 1.0f, gh = my1 - g1.y + 1.0f;
      float gcx = g1.x + 0.5f * gw, gcy = g1.y + 0.5f * gh;
      float t0 = (gcx - acx) * raw, t1v = (gcy - acy) * rah;
      float t2 = logf(gw * raw), t3 = logf(gh * rah);
      t_bbox += huber9(d4 - t0) + huber9(d5 - t1v) + huber9(d6 - t2) + huber9(d7 - t3);
      t_nfg += 1.f;
    }

    // ---- IoU L1 loss ----
    if (fg0) t_iou += fabsf(riv0 - aval);
    if (fg1) t_iou += fabsf(riv1 - fmaxf(bval, 0.0f));

    // ---- num softmax loss ----
    {
      int nl = ((lab0 > 0.f) ? 1 : 0) + ((lab1 > 0.f) ? 1 : 0) - 1;
      if (nl != -1) {
        float m = fmaxf(sn0, sn1);
        float lse = m + logf(expf(sn0 - m) + expf(sn1 - m));
        float picked = ((nl == 0) ? sn0 : sn1) - lse;
        t_num -= picked;
        t_ncnt += 1.f;
      }
    }
  }

  // block reduction: wave shuffle -> LDS -> one double atomic per scalar
  float vals[7] = {t_cls, t_bbox, t_iou, t_num, t_npos, t_nfg, t_ncnt};
  int lane = threadIdx.x & 63;
  int wid = threadIdx.x >> 6;
#pragma unroll
  for (int k = 0; k < 7; ++k) {
    float s = waveSum(vals[k]);
    if (lane == 0) sRed[wid][k] = s;
  }
  __syncthreads();
  if (threadIdx.x < 7) {
    double s = (double)sRed[0][threadIdx.x] + (double)sRed[1][threadIdx.x] +
               (double)sRed[2][threadIdx.x] + (double)sRed[3][threadIdx.x];
    atomicAdd(&acc[threadIdx.x * 16], s);  // 128 B apart, device-scope
    __threadfence();                       // release our adds device-wide
  }
  __syncthreads();
  if (threadIdx.x == 0) {
    unsigned int old = atomicAdd(cnt, 1u); // ticket; device-scope
    sLast = (old == (unsigned int)(totalBlocks - 1)) ? 1 : 0;
  }
  __syncthreads();

  // last block finalizes: read accumulators through the atomic domain
  if (sLast && threadIdx.x == 0) {
    __threadfence();
    double cls  = atomicAdd(&acc[0 * 16], 0.0);
    double bbox = atomicAdd(&acc[1 * 16], 0.0);
    double iou  = atomicAdd(&acc[2 * 16], 0.0);
    double num  = atomicAdd(&acc[3 * 16], 0.0);
    double npos = atomicAdd(&acc[4 * 16], 0.0);
    double nfg  = atomicAdd(&acc[5 * 16], 0.0);
    double ncnt = atomicAdd(&acc[6 * 16], 0.0);
    double dpos = npos > 1.0 ? npos : 1.0;
    double dfg  = nfg  > 1.0 ? nfg  : 1.0;
    double dcnt = ncnt > 1.0 ? ncnt : 1.0;
    out[0] = (float)(cls / dpos);
    out[1] = (float)(2.0 * bbox / dfg);
    out[2] = (float)(2.0 * iou / dfg);
    out[3] = (float)(num / dcnt);
  }
}

extern "C" void kernel_launch(void* const* d_in, const int* in_sizes, int n_in,
                              void* d_out, int out_size, void* d_ws, size_t ws_size,
                              hipStream_t stream) {
  const float* pred_cls = (const float*)d_in[0];
  const float* rpn_num  = (const float*)d_in[1];
  const float* pred_reg = (const float*)d_in[2];
  const float* anchors  = (const float*)d_in[3];
  const float* rpn_iou  = (const float*)d_in[4];
  const float* boxes    = (const float*)d_in[5];
  // d_in[6] = im_info: unused by the reference math

  int A = in_sizes[3] / 4;
  int n = in_sizes[0] / (2 * A);
  int G = in_sizes[5] / (5 * n);

  double* acc = (double*)d_ws;                       // 7 x stride-16 doubles
  unsigned int* cnt = (unsigned int*)((char*)d_ws + 7 * 16 * sizeof(double));
  hipMemsetAsync(d_ws, 0, 7 * 16 * sizeof(double) + sizeof(unsigned int), stream);

  int nBx = (A + 63) / 64;
  int totalBlocks = nBx * n;
  dim3 grid(nBx, n, 1);  // 64 anchors/block x SPLIT=4 lanes
  retina_main<<<grid, dim3(256, 1, 1), 0, stream>>>(
      pred_cls, rpn_num, pred_reg, anchors, rpn_iou, boxes,
      A, G, totalBlocks, acc, cnt, (float*)d_out);
}

// Round 6
// 179.277 us; speedup vs baseline: 1.5859x; 1.0368x over previous
//
#include <hip/hip_runtime.h>
#include <math.h>

#define G_MAX 512   // LDS capacity for GT boxes; setup uses G=300
#define SPLIT 4     // threads per anchor (g-loop split)

__device__ __forceinline__ float waveSum(float v) {
#pragma unroll
  for (int o = 32; o > 0; o >>= 1) v += __shfl_down(v, o, 64);
  return v;
}

// smooth-L1 with sigma=3 (s2=9)
__device__ __forceinline__ float huber9(float x) {
  float ax = fabsf(x);
  return (ax < (1.0f / 9.0f)) ? 4.5f * x * x : ax - (0.5f / 9.0f);
}

// Exact IoU in the reference's op order. g = (x0, y0, x1+1, y1+1)
__device__ __forceinline__ float iouExact(float bx0, float by0, float bx1, float by1,
                                          float areab, float4 g, float areag) {
  float gx1 = g.z - 1.0f, gy1 = g.w - 1.0f;  // exact inverse of the staged +1
  float iw = fminf(bx1, gx1) - fmaxf(bx0, g.x) + 1.0f;
  float ih = fminf(by1, gy1) - fmaxf(by0, g.y) + 1.0f;
  float inter = fmaxf(iw, 0.f) * fmaxf(ih, 0.f);
  float uni = areab + areag - inter;
  return inter / fmaxf(uni, 1.0f);
}

// Inverse comparison key: key = (areaB+areaG)*rcp(inter); argmax iou == argmin
// key (uint compare on positive floats). ONE-CLAMP trick: inter = max(iw,0)*ih.
//   ih >= 0: identical to the two-clamp value (positive-overlap keys exact).
//   ih <  0: inter <= -0 -> key negative or -inf -> uint >= 0x80000000 ->
//            ranks below ALL positive keys under min-tracking, i.e. in the
//            zero-overlap class, whose internal order is output-invariant
//            (winners are recomputed exactly with validity masks; all
//            zero-overlap/invalid picks yield label 0 / fg=false / value 0).
// Low 9 bits carry g: min-ties resolve to smallest g (jax stable semantics).
// Never NaN: S>0 finite, S*(+-inf)=+-inf.
__device__ __forceinline__ uint32_t packKey(float x0, float y0, float x1p, float y1p,
                                            float area, float4 gb, float ga,
                                            uint32_t g) {
  float iw = fminf(x1p, gb.z) - fmaxf(x0, gb.x);
  float ih = fminf(y1p, gb.w) - fmaxf(y0, gb.y);
  float inter = fmaxf(iw, 0.f) * ih;
  float key = (area + ga) * __builtin_amdgcn_rcpf(inter);
  return (__float_as_uint(key) & 0xFFFFFE00u) | g;
}

__global__ __launch_bounds__(256) void retina_main(
    const float* __restrict__ pred_cls,   // (n, A, 2)
    const float* __restrict__ rpn_num,    // (n, A, 2)
    const float* __restrict__ pred_reg,   // (n, A, 8)
    const float* __restrict__ anchors,    // (A, 4)
    const float* __restrict__ rpn_iou,    // (n, A, 2)
    const float* __restrict__ boxes,      // (n, G, 5)
    int A, int G, int totalBlocks,
    double* __restrict__ acc,             // 7 accumulators, stride 16 doubles
    unsigned int* __restrict__ cnt,       // ticket counter (zeroed)
    float* __restrict__ out)              // 4 floats
{
  __shared__ float4 sBox[G_MAX];  // x0, y0, x1+1, y1+1
  __shared__ float sA[G_MAX];     // area (1e30 for invalid/dummy)
  __shared__ float sRed[4][7];
  __shared__ int sLast;

  const int img = blockIdx.y;
  const int seg = threadIdx.x & (SPLIT - 1);
  const int al  = threadIdx.x >> 2;          // anchor-local 0..63
  const int i   = blockIdx.x * 64 + al;
  const int ic  = (i < A) ? i : (A - 1);

  const int len  = (G + SPLIT - 1) / SPLIT;
  const int padG = len * SPLIT;              // <= G_MAX

  // stage GT boxes (pad range with inert dummies: area=1e30)
  const float* gtb = boxes + (size_t)img * G * 5;
  for (int g = threadIdx.x; g < padG; g += 256) {
    if (g < G) {
      float x0 = gtb[g * 5 + 0], y0 = gtb[g * 5 + 1];
      float x1 = gtb[g * 5 + 2], y1 = gtb[g * 5 + 3];
      float lb = gtb[g * 5 + 4];
      sBox[g] = make_float4(x0, y0, x1 + 1.0f, y1 + 1.0f);
      sA[g] = (lb != -1.0f) ? (x1 - x0 + 1.0f) * (y1 - y0 + 1.0f) : 1e30f;
    } else {
      sBox[g] = make_float4(0.f, 0.f, 1.f, 1.f);
      sA[g] = 1e30f;
    }
  }
  __syncthreads();

  float t_cls = 0.f, t_bbox = 0.f, t_iou = 0.f, t_num = 0.f;
  float t_npos = 0.f, t_nfg = 0.f, t_ncnt = 0.f;

  const float BBOX_CLIP = 4.1351666f;  // log(1000/16)

  // per-anchor data (4 lanes share one anchor; redundant loads hit L1)
  float ax0 = anchors[ic * 4 + 0], ay0 = anchors[ic * 4 + 1];
  float ax1 = anchors[ic * 4 + 2], ay1 = anchors[ic * 4 + 3];
  float aw = ax1 - ax0 + 1.0f, ah = ay1 - ay0 + 1.0f;
  float areaa = aw * ah;
  float acx = ax0 + 0.5f * aw, acy = ay0 + 0.5f * ah;
  float ax1p = ax1 + 1.0f, ay1p = ay1 + 1.0f;

  const float* dp = pred_reg + ((size_t)img * A + ic) * 8;
  float d0 = dp[0], d1 = dp[1], d2 = dp[2], d3 = dp[3];
  float d4 = dp[4], d5 = dp[5], d6 = dp[6], d7 = dp[7];

  // epilogue-only inputs: issue early (exec-masked to seg 0) to hide latency
  float pcv0 = 0.f, pcv1 = 0.f, riv0 = 0.f, riv1 = 0.f, sn0 = 0.f, sn1 = 0.f;
  if (seg == 0) {
    const float* pc = pred_cls + ((size_t)img * A + ic) * 2;
    pcv0 = pc[0]; pcv1 = pc[1];
    const float* ri = rpn_iou + ((size_t)img * A + ic) * 2;
    riv0 = ri[0]; riv1 = ri[1];
    const float* sp = rpn_num + ((size_t)img * A + ic) * 2;
    sn0 = sp[0]; sn1 = sp[1];
  }

  // decode predicted boxes
  float p0cx = acx + d0 * aw, p0cy = acy + d1 * ah;
  float p0w = aw * expf(fminf(d2, BBOX_CLIP));
  float p0h = ah * expf(fminf(d3, BBOX_CLIP));
  float b0x0 = p0cx - 0.5f * p0w, b0y0 = p0cy - 0.5f * p0h;
  float b0x1 = p0cx + 0.5f * p0w, b0y1 = p0cy + 0.5f * p0h;
  float area0 = (b0x1 - b0x0 + 1.0f) * (b0y1 - b0y0 + 1.0f);
  float b0x1p = b0x1 + 1.0f, b0y1p = b0y1 + 1.0f;

  float p1cx = acx + d4 * aw, p1cy = acy + d5 * ah;
  float p1w = aw * expf(fminf(d6, BBOX_CLIP));
  float p1h = ah * expf(fminf(d7, BBOX_CLIP));
  float b1x0 = p1cx - 0.5f * p1w, b1y0 = p1cy - 0.5f * p1h;
  float b1x1 = p1cx + 0.5f * p1w, b1y1 = p1cy + 0.5f * p1h;
  float area1 = (b1x1 - b1x0 + 1.0f) * (b1y1 - b1y0 + 1.0f);
  float b1x1p = b1x1 + 1.0f, b1y1p = b1y1 + 1.0f;

  // min-trackers over inverse keys (merge-associative)
  uint32_t an1 = 0xFFFFFFFFu, an2 = 0xFFFFFFFFu;   // anchor-vs-gt best/2nd
  uint32_t am  = 0xFFFFFFFFu;                      // decoded box 0 best
  uint32_t bk1 = 0xFFFFFFFFu, bk2 = 0xFFFFFFFFu;   // decoded box 1 best/2nd

  int g = seg * len;
#pragma unroll 15
  for (int t = 0; t < len; ++t, ++g) {
    float4 gb = sBox[g];
    float ga = sA[g];
    uint32_t gu = (uint32_t)g;
    {
      uint32_t p = packKey(ax0, ay0, ax1p, ay1p, areaa, gb, ga, gu);
      uint32_t hi = max(p, an1);
      an1 = min(an1, p);
      an2 = min(an2, hi);
    }
    {
      uint32_t p = packKey(b0x0, b0y0, b0x1p, b0y1p, area0, gb, ga, gu);
      am = min(am, p);
    }
    {
      uint32_t p = packKey(b1x0, b1y0, b1x1p, b1y1p, area1, gb, ga, gu);
      uint32_t hi = max(p, bk1);
      bk1 = min(bk1, p);
      bk2 = min(bk2, hi);
    }
  }

  // butterfly merge across the 4 lanes of this anchor
#pragma unroll
  for (int m = 1; m <= 2; m <<= 1) {
    uint32_t o1 = (uint32_t)__shfl_xor((int)an1, m, 64);
    uint32_t o2 = (uint32_t)__shfl_xor((int)an2, m, 64);
    uint32_t hi = max(an1, o1);
    an1 = min(an1, o1);
    an2 = min(min(an2, o2), hi);

    am = min(am, (uint32_t)__shfl_xor((int)am, m, 64));

    uint32_t q1 = (uint32_t)__shfl_xor((int)bk1, m, 64);
    uint32_t q2 = (uint32_t)__shfl_xor((int)bk2, m, 64);
    uint32_t hib = max(bk1, q1);
    bk1 = min(bk1, q1);
    bk2 = min(min(bk2, q2), hib);
  }

  if (seg == 0 && i < A) {
    // winning indices; clamp defensively to the initialized LDS range
    int pg1 = padG - 1;
    int i0 = min((int)(an1 & 0x1FFu), pg1);
    int i1 = min((int)(an2 & 0x1FFu), pg1);
    int ai = min((int)(am  & 0x1FFu), pg1);
    int bi = min((int)(bk1 & 0x1FFu), pg1);
    int bi2= min((int)(bk2 & 0x1FFu), pg1);

    // exact recompute of winning values (reference op order, explicit validity)
    float4 g0 = sBox[i0]; float a0 = sA[i0]; bool val0 = a0 < 1e29f;
    float v0 = val0 ? iouExact(ax0, ay0, ax1, ay1, areaa, g0, a0) : -1.0f;
    float4 g1 = sBox[i1]; float a1 = sA[i1]; bool val1 = a1 < 1e29f;
    float v1 = val1 ? iouExact(ax0, ay0, ax1, ay1, areaa, g1, a1) : -1.0f;
    float4 ga4 = sBox[ai]; float aav = sA[ai];
    float aval = (aav < 1e29f) ? iouExact(b0x0, b0y0, b0x1, b0y1, area0, ga4, aav) : 0.0f;
    int bIdx = (ai == bi) ? bi2 : bi;  // b with b[ai] zeroed, then argmax
    float4 gb4 = sBox[bIdx]; float abv = sA[bIdx];
    float bval = (abv < 1e29f) ? iouExact(b1x0, b1y0, b1x1, b1y1, area1, gb4, abv) : 0.0f;

    // labels: >=0.5 -> 1, <0.4 -> 0, else -1
    float la  = (v0 >= 0.5f) ? 1.0f : ((v0 < 0.4f) ? 0.0f : -1.0f);
    float lbv = (v1 >= 0.5f) ? 1.0f : ((v1 < 0.4f) ? 0.0f : -1.0f);
    float lab0 = la;
    float lab1 = lbv - (((la == 0.0f) && (lbv != 0.0f)) ? 1.0f : 0.0f);

    // ---- focal classification loss ----
    {
      float p = pcv0;
      if (lab0 != -1.0f) {
        float l = (lab0 == 1.0f)
                      ? 0.25f * (1.0f - p) * (1.0f - p) * logf(p)
                      : 0.75f * p * p * logf(1.0f - p);
        t_cls -= l;
      }
      if (lab0 > 0.f) t_npos += 1.f;
      float q = pcv1;
      if (lab1 != -1.0f) {
        float l = (lab1 == 1.0f)
                      ? 0.25f * (1.0f - q) * (1.0f - q) * logf(q)
                      : 0.75f * q * q * logf(1.0f - q);
        t_cls -= l;
      }
      if (lab1 > 0.f) t_npos += 1.f;
    }

    bool fg0 = (lab0 != 0.0f) && (lab0 != -1.0f);
    bool fg1 = (lab1 != 0.0f) && (lab1 != -1.0f);

    // fast reciprocals for the bbox-target divides (rel err ~1e-7, harmless)
    float raw = __builtin_amdgcn_rcpf(aw), rah = __builtin_amdgcn_rcpf(ah);

    // ---- bbox smooth-L1 vs bbox_transform(anchor, matched gt) ----
    if (fg0) {
      float mx1 = g0.z - 1.0f, my1 = g0.w - 1.0f;
      float gw = mx1 - g0.x + 1.0f, gh = my1 - g0.y + 1.0f;
      float gcx = g0.x + 0.5f * gw, gcy = g0.y + 0.5f * gh;
      float t0 = (gcx - acx) * raw, t1v = (gcy - acy) * rah;
      float t2 = logf(gw * raw), t3 = logf(gh * rah);
      t_bbox += huber9(d0 - t0) + huber9(d1 - t1v) + huber9(d2 - t2) + huber9(d3 - t3);
      t_nfg += 1.f;
    }
    if (fg1) {
      float mx1 = g1.z - 1.0f, my1 = g1.w - 1.0f;
      float gw = mx1 - g1.x + 1.0f, gh = my1 - g1.y + 1.0f;
      float gcx = g1.x + 0.5f * gw, gcy = g1.y + 0.5f * gh;
      float t0 = (gcx - acx) * raw, t1v = (gcy - acy) * rah;
      float t2 = logf(gw * raw), t3 = logf(gh * rah);
      t_bbox += huber9(d4 - t0) + huber9(d5 - t1v) + huber9(d6 - t2) + huber9(d7 - t3);
      t_nfg += 1.f;
    }

    // ---- IoU L1 loss ----
    if (fg0) t_iou += fabsf(riv0 - aval);
    if (fg1) t_iou += fabsf(riv1 - fmaxf(bval, 0.0f));

    // ---- num softmax loss ----
    {
      int nl = ((lab0 > 0.f) ? 1 : 0) + ((lab1 > 0.f) ? 1 : 0) - 1;
      if (nl != -1) {
        float m = fmaxf(sn0, sn1);
        float lse = m + logf(expf(sn0 - m) + expf(sn1 - m));
        float picked = ((nl == 0) ? sn0 : sn1) - lse;
        t_num -= picked;
        t_ncnt += 1.f;
      }
    }
  }

  // block reduction: wave shuffle -> LDS -> one double atomic per scalar
  float vals[7] = {t_cls, t_bbox, t_iou, t_num, t_npos, t_nfg, t_ncnt};
  int lane = threadIdx.x & 63;
  int wid = threadIdx.x >> 6;
#pragma unroll
  for (int k = 0; k < 7; ++k) {
    float s = waveSum(vals[k]);
    if (lane == 0) sRed[wid][k] = s;
  }
  __syncthreads();
  if (threadIdx.x < 7) {
    double s = (double)sRed[0][threadIdx.x] + (double)sRed[1][threadIdx.x] +
               (double)sRed[2][threadIdx.x] + (double)sRed[3][threadIdx.x];
    atomicAdd(&acc[threadIdx.x * 16], s);  // 128 B apart, device-scope
    __threadfence();                       // release our adds device-wide
  }
  __syncthreads();
  if (threadIdx.x == 0) {
    unsigned int old = atomicAdd(cnt, 1u); // ticket; device-scope
    sLast = (old == (unsigned int)(totalBlocks - 1)) ? 1 : 0;
  }
  __syncthreads();

  // last block finalizes: read accumulators through the atomic domain
  if (sLast && threadIdx.x == 0) {
    __threadfence();
    double cls  = atomicAdd(&acc[0 * 16], 0.0);
    double bbox = atomicAdd(&acc[1 * 16], 0.0);
    double iou  = atomicAdd(&acc[2 * 16], 0.0);
    double num  = atomicAdd(&acc[3 * 16], 0.0);
    double npos = atomicAdd(&acc[4 * 16], 0.0);
    double nfg  = atomicAdd(&acc[5 * 16], 0.0);
    double ncnt = atomicAdd(&acc[6 * 16], 0.0);
    double dpos = npos > 1.0 ? npos : 1.0;
    double dfg  = nfg  > 1.0 ? nfg  : 1.0;
    double dcnt = ncnt > 1.0 ? ncnt : 1.0;
    out[0] = (float)(cls / dpos);
    out[1] = (float)(2.0 * bbox / dfg);
    out[2] = (float)(2.0 * iou / dfg);
    out[3] = (float)(num / dcnt);
  }
}

extern "C" void kernel_launch(void* const* d_in, const int* in_sizes, int n_in,
                              void* d_out, int out_size, void* d_ws, size_t ws_size,
                              hipStream_t stream) {
  const float* pred_cls = (const float*)d_in[0];
  const float* rpn_num  = (const float*)d_in[1];
  const float* pred_reg = (const float*)d_in[2];
  const float* anchors  = (const float*)d_in[3];
  const float* rpn_iou  = (const float*)d_in[4];
  const float* boxes    = (const float*)d_in[5];
  // d_in[6] = im_info: unused by the reference math

  int A = in_sizes[3] / 4;
  int n = in_sizes[0] / (2 * A);
  int G = in_sizes[5] / (5 * n);

  double* acc = (double*)d_ws;                       // 7 x stride-16 doubles
  unsigned int* cnt = (unsigned int*)((char*)d_ws + 7 * 16 * sizeof(double));
  hipMemsetAsync(d_ws, 0, 7 * 16 * sizeof(double) + sizeof(unsigned int), stream);

  int nBx = (A + 63) / 64;
  int totalBlocks = nBx * n;
  dim3 grid(nBx, n, 1);  // 64 anchors/block x SPLIT=4 lanes
  retina_main<<<grid, dim3(256, 1, 1), 0, stream>>>(
      pred_cls, rpn_num, pred_reg, anchors, rpn_iou, boxes,
      A, G, totalBlocks, acc, cnt, (float*)d_out);
}